// Round 1
// baseline (212.209 us; speedup 1.0000x reference)
//
#include <hip/hip_runtime.h>
#include <math.h>

// Problem constants (fixed by reference)
#define GRIDN   14
#define BOXN    2
#define LABELN  20
#define ALL_BOX 10         // 5*BOXN
#define CCH     30         // ALL_BOX + LABELN channels per cell
#define CELLS_PER_BLOCK 256

__global__ void yolo_zero_kernel(float* out, int n) {
    int i = blockIdx.x * blockDim.x + threadIdx.x;
    if (i < n) out[i] = 0.0f;
}

__global__ __launch_bounds__(256) void yolo_loss_kernel(
    const float* __restrict__ preds,
    const float* __restrict__ truths,
    float* __restrict__ out,
    int ncells)
{
#pragma clang fp contract(off)
    // LDS staging: 256 cells * 30 ch * 4B = 30720 B per tensor (61440 total -> 2 blocks/CU)
    __shared__ float sP[CELLS_PER_BLOCK * CCH];
    __shared__ float sT[CELLS_PER_BLOCK * CCH];
    __shared__ float wsum[4];

    const int tid = threadIdx.x;
    const long long base = (long long)blockIdx.x * (CELLS_PER_BLOCK * CCH);

    // Coalesced float4 staging (chunk base is 16B-aligned: 30720 % 16 == 0)
    const float4* gp = (const float4*)(preds + base);
    const float4* gt = (const float4*)(truths + base);
    float4* lp = (float4*)sP;
    float4* lt = (float4*)sT;
    constexpr int NV4 = CELLS_PER_BLOCK * CCH / 4;  // 1920
#pragma unroll
    for (int i = 0; i < (NV4 + 255) / 256; ++i) {
        int idx = tid + i * 256;
        if (idx < NV4) { lp[idx] = gp[idx]; lt[idx] = gt[idx]; }
    }
    __syncthreads();

    float cell_loss = 0.0f;
    const long long cell = (long long)blockIdx.x * CELLS_PER_BLOCK + tid;
    if (cell < ncells) {
        const float* p = sP + tid * CCH;
        const float* t = sT + tid * CCH;

        const float CELL = (float)(1.0 / (double)GRIDN);

        const float tx = t[0], ty = t[1], tw = t[2], th_ = t[3], tconf = t[4];
        const bool obj = tconf > 0.0f;

        // Truth box (scaled center, half-extent) — same op order as reference
        const float tcx = CELL * tx, tcy = CELL * ty;
        const float thx = tw * 0.5f, thy = th_ * 0.5f;
        const float tltx = tcx - thx, tlty = tcy - thy;
        const float trbx = tcx + thx, trby = tcy + thy;
        const float ta = (trbx - tltx) * (trby - tlty);

        float iou[BOXN], conf[BOXN];
        float pr[BOXN][5];
#pragma unroll
        for (int b = 0; b < BOXN; ++b) {
            const float bx = p[b * 5 + 0], by = p[b * 5 + 1];
            const float bw = p[b * 5 + 2], bh = p[b * 5 + 3];
            const float bc = p[b * 5 + 4];
            pr[b][0] = bx; pr[b][1] = by; pr[b][2] = bw; pr[b][3] = bh; pr[b][4] = bc;
            conf[b] = bc;
            const float pcx = CELL * bx, pcy = CELL * by;
            const float phx = bw * 0.5f, phy = bh * 0.5f;
            const float pltx = pcx - phx, plty = pcy - phy;
            const float prbx = pcx + phx, prby = pcy + phy;
            const float ltx = fmaxf(pltx, tltx), lty = fmaxf(plty, tlty);
            const float rbx = fminf(prbx, trbx), rby = fminf(prby, trby);
            const float whx = fmaxf(rbx - ltx, 0.0f);
            const float why = fmaxf(rby - lty, 0.0f);
            const float inter = whx * why;
            const float pa = (prbx - pltx) * (prby - plty);
            iou[b] = inter / (pa + ta - inter);
        }

        const float max_iou = fmaxf(iou[0], iou[1]);
        // Responsible-box selection, replicating jnp argmax first-occurrence + tie rule:
        //   n_tied > 1  -> argmax over conf among tied (first on conf tie)
        //   else        -> argmax over iou
        int resp;
        if (iou[0] == iou[1]) resp = (conf[0] >= conf[1]) ? 0 : 1;
        else                  resp = (iou[0] > iou[1]) ? 0 : 1;

        const float* prr = pr[resp];

        const float dcx = prr[0] - tx;
        const float dcy = prr[1] - ty;
        const float center = dcx * dcx + dcy * dcy;

        const float dsx = sqrtf(prr[2]) - sqrtf(tw);
        const float dsy = sqrtf(prr[3]) - sqrtf(th_);
        const float size = dsx * dsx + dsy * dsy;

        const float dconf = prr[4] - max_iou;
        const float conf_resp = dconf * dconf;

        const float c_other = conf[1 - resp];
        const float conf_noresp = c_other * c_other;

        const float conf_noobj = conf[0] * conf[0] + conf[1] * conf[1];

        float label = 0.0f;
#pragma unroll
        for (int k = ALL_BOX; k < CCH; ++k) {
            const float d = p[k] - t[k];
            label += d * d;
        }

        const float w  = obj ? 1.0f : 0.0f;
        const float nw = obj ? 0.0f : 1.0f;
        cell_loss = w * (5.0f * (center + size) + conf_resp + 0.5f * conf_noresp + label)
                  + nw * (0.5f * conf_noobj);
    }

    // Block reduction: wave64 shuffle -> LDS across 4 waves -> one atomic per block
    float v = cell_loss;
#pragma unroll
    for (int off = 32; off > 0; off >>= 1) v += __shfl_down(v, off, 64);
    const int wid = tid >> 6, lane = tid & 63;
    if (lane == 0) wsum[wid] = v;
    __syncthreads();
    if (tid == 0) {
        const float s = (wsum[0] + wsum[1]) + (wsum[2] + wsum[3]);
        atomicAdd(out, s * (1.0f / 4096.0f));
    }
}

extern "C" void kernel_launch(void* const* d_in, const int* in_sizes, int n_in,
                              void* d_out, int out_size, void* d_ws, size_t ws_size,
                              hipStream_t stream) {
    const float* preds  = (const float*)d_in[0];
    const float* truths = (const float*)d_in[1];
    float* out = (float*)d_out;

    const int ncells = in_sizes[0] / CCH;          // 4096*14*14 = 802816
    const int blocks = ncells / CELLS_PER_BLOCK;   // 3136 (exact)

    // d_out is re-poisoned before every timed launch -> zero it on-stream first.
    yolo_zero_kernel<<<(out_size + 255) / 256, 256, 0, stream>>>(out, out_size);
    yolo_loss_kernel<<<blocks, 256, 0, stream>>>(preds, truths, out, ncells);
}

// Round 2
// 206.360 us; speedup vs baseline: 1.0283x; 1.0283x over previous
//
#include <hip/hip_runtime.h>
#include <math.h>

// Problem constants (fixed by reference)
#define GRIDN   14
#define BOXN    2
#define LABELN  20
#define ALL_BOX 10         // 5*BOXN
#define CCH     30         // ALL_BOX + LABELN channels per cell
#define CELLS_PER_BLOCK 256

__global__ void yolo_zero_kernel(float* out, int n) {
    int i = blockIdx.x * blockDim.x + threadIdx.x;
    if (i < n) out[i] = 0.0f;
}

// Async global->LDS DMA, 16B per lane, wave-uniform LDS base + lane*16.
// (guide §5: width=16 emits global_load_lds_dwordx4; no VGPR round-trip)
__device__ __forceinline__ void async_load16(const float* g, float* l) {
    __builtin_amdgcn_global_load_lds(
        (const __attribute__((address_space(1))) void*)g,
        (__attribute__((address_space(3))) void*)l,
        16, 0, 0);
}

__global__ __launch_bounds__(256) void yolo_loss_kernel(
    const float* __restrict__ preds,
    const float* __restrict__ truths,
    float* __restrict__ out,
    int ncells)
{
#pragma clang fp contract(off)
    // LDS staging: 256 cells * 30 ch * 4B = 30720 B per tensor (61440 total -> 2 blocks/CU)
    __shared__ float sP[CELLS_PER_BLOCK * CCH];
    __shared__ float sT[CELLS_PER_BLOCK * CCH];
    __shared__ float wsum[4];

    const int tid  = threadIdx.x;
    const int wave = tid >> 6;
    const int lane = tid & 63;
    const long long base = (long long)blockIdx.x * (CELLS_PER_BLOCK * CCH);

    // 60 chunks of 1 KB (256 floats): 0..29 -> preds, 30..59 -> truths.
    // Each wave issues 15 global_load_lds_dwordx4; all 15 stay in flight
    // (no data VGPRs), drained by the vmcnt(0) the compiler emits at the barrier.
#pragma unroll
    for (int i = 0; i < 15; ++i) {
        const int c = wave + i * 4;                 // wave-uniform chunk id
        const float* gsrc;
        float* ldst;
        if (c < 30) { gsrc = preds  + base + (long long)c * 256;        ldst = sP + c * 256; }
        else        { gsrc = truths + base + (long long)(c - 30) * 256; ldst = sT + (c - 30) * 256; }
        async_load16(gsrc + lane * 4, ldst);
    }
    __syncthreads();

    float cell_loss = 0.0f;
    const long long cell = (long long)blockIdx.x * CELLS_PER_BLOCK + tid;
    if (cell < ncells) {
        const float* p = sP + tid * CCH;
        const float* t = sT + tid * CCH;

        const float CELL = (float)(1.0 / (double)GRIDN);

        const float tx = t[0], ty = t[1], tw = t[2], th_ = t[3], tconf = t[4];
        const bool obj = tconf > 0.0f;

        // Truth box (scaled center, half-extent) — same op order as reference
        const float tcx = CELL * tx, tcy = CELL * ty;
        const float thx = tw * 0.5f, thy = th_ * 0.5f;
        const float tltx = tcx - thx, tlty = tcy - thy;
        const float trbx = tcx + thx, trby = tcy + thy;
        const float ta = (trbx - tltx) * (trby - tlty);

        float iou[BOXN], conf[BOXN];
        float pr[BOXN][5];
#pragma unroll
        for (int b = 0; b < BOXN; ++b) {
            const float bx = p[b * 5 + 0], by = p[b * 5 + 1];
            const float bw = p[b * 5 + 2], bh = p[b * 5 + 3];
            const float bc = p[b * 5 + 4];
            pr[b][0] = bx; pr[b][1] = by; pr[b][2] = bw; pr[b][3] = bh; pr[b][4] = bc;
            conf[b] = bc;
            const float pcx = CELL * bx, pcy = CELL * by;
            const float phx = bw * 0.5f, phy = bh * 0.5f;
            const float pltx = pcx - phx, plty = pcy - phy;
            const float prbx = pcx + phx, prby = pcy + phy;
            const float ltx = fmaxf(pltx, tltx), lty = fmaxf(plty, tlty);
            const float rbx = fminf(prbx, trbx), rby = fminf(prby, trby);
            const float whx = fmaxf(rbx - ltx, 0.0f);
            const float why = fmaxf(rby - lty, 0.0f);
            const float inter = whx * why;
            const float pa = (prbx - pltx) * (prby - plty);
            iou[b] = inter / (pa + ta - inter);
        }

        const float max_iou = fmaxf(iou[0], iou[1]);
        // Responsible-box selection, replicating jnp argmax first-occurrence + tie rule:
        //   n_tied > 1  -> argmax over conf among tied (first on conf tie)
        //   else        -> argmax over iou
        int resp;
        if (iou[0] == iou[1]) resp = (conf[0] >= conf[1]) ? 0 : 1;
        else                  resp = (iou[0] > iou[1]) ? 0 : 1;

        const float* prr = pr[resp];

        const float dcx = prr[0] - tx;
        const float dcy = prr[1] - ty;
        const float center = dcx * dcx + dcy * dcy;

        const float dsx = sqrtf(prr[2]) - sqrtf(tw);
        const float dsy = sqrtf(prr[3]) - sqrtf(th_);
        const float size = dsx * dsx + dsy * dsy;

        const float dconf = prr[4] - max_iou;
        const float conf_resp = dconf * dconf;

        const float c_other = conf[1 - resp];
        const float conf_noresp = c_other * c_other;

        const float conf_noobj = conf[0] * conf[0] + conf[1] * conf[1];

        float label = 0.0f;
#pragma unroll
        for (int k = ALL_BOX; k < CCH; ++k) {
            const float d = p[k] - t[k];
            label += d * d;
        }

        const float w  = obj ? 1.0f : 0.0f;
        const float nw = obj ? 0.0f : 1.0f;
        cell_loss = w * (5.0f * (center + size) + conf_resp + 0.5f * conf_noresp + label)
                  + nw * (0.5f * conf_noobj);
    }

    // Block reduction: wave64 shuffle -> LDS across 4 waves -> one atomic per block
    float v = cell_loss;
#pragma unroll
    for (int off = 32; off > 0; off >>= 1) v += __shfl_down(v, off, 64);
    if (lane == 0) wsum[wave] = v;
    __syncthreads();
    if (tid == 0) {
        const float s = (wsum[0] + wsum[1]) + (wsum[2] + wsum[3]);
        atomicAdd(out, s * (1.0f / 4096.0f));
    }
}

extern "C" void kernel_launch(void* const* d_in, const int* in_sizes, int n_in,
                              void* d_out, int out_size, void* d_ws, size_t ws_size,
                              hipStream_t stream) {
    const float* preds  = (const float*)d_in[0];
    const float* truths = (const float*)d_in[1];
    float* out = (float*)d_out;

    const int ncells = in_sizes[0] / CCH;          // 4096*14*14 = 802816
    const int blocks = ncells / CELLS_PER_BLOCK;   // 3136 (exact)

    // d_out is re-poisoned before every timed launch -> zero it on-stream first.
    yolo_zero_kernel<<<(out_size + 255) / 256, 256, 0, stream>>>(out, out_size);
    yolo_loss_kernel<<<blocks, 256, 0, stream>>>(preds, truths, out, ncells);
}